// Round 9
// baseline (1219.247 us; speedup 1.0000x reference)
//
#include <hip/hip_runtime.h>

// Decoder GRU, B=128 T=512 X=64 H=256, skip runtime (skip==0 -> generic
// path).  Round 15: col-pair x K-quarter remap to halve LDS delivery.
//
// R12-R14: three stall fixes (conflicts->0, fences removed, vmcnt-free
// barrier) all null at ~4880 cyc/step -> kernel is LDS-DELIVERY bound:
// per-CU LDS port (~128B/cyc) must move ~300KB/step (wn stream 128KB +
// h fan-out 128KB (256B/lane!) + x 16KB + pt 32KB) ~= 2400 cyc.
// Fix: thread role (c=t>>1, kh=t&1) -> (cp=t>>2 owns cols {2cp,2cp+1},
// kq=t&3 owns a K-quarter).  h bytes/lane halve (128B) -> h fan-out 64KB;
// x halves; a thread finalizes BOTH its columns (no DPP moves for the
// hid/pt writes); reduce = 2-stage DPP quad butterfly.  dot2 count/thread
// unchanged (240); resident regs unchanged (rz 128 + ih 48 + wout 16).
// wn n-gate stream stays 128KB (the next target if this lands).
// Staggered LDS blocks (h: 36-word, x: 12-word) put the 4 kq quad-read
// addresses on disjoint banks.  pt2/PROJ path byte-identical to R13/R14
// (verified, 0 conflicts).  Main loop: 1 lgkm-only barrier per step.
typedef _Float16 h2_t __attribute__((ext_vector_type(2)));

constexpr int T_ = 512;
constexpr int X_ = 64;
constexpr int H_ = 256;
constexpr int NWG = 128;  // 1 batch per WG, 1 WG/CU
constexpr int NT = 512;   // 8 waves = 2/EU
constexpr int RS = 16;    // ring slots; lookback 2*skip, OK for skip <= 7

// fp16 weight image in d_ws (uint4 units), [u][t], cp=t>>2, kq=t&3:
//   u  0..31 : W_hh r,z : g=u>>4, col01=(u>>3)&1, j=u&7
//              row = g*256 + 2cp+col01, k = kq*64 + j*8
//   u 32..47 : W_hh n (LDS stream): col01=(u-32)>>3, j=(u-32)&7
//   u 48..59 : W_ih: g=(u-48)>>2, col01=((u-48)>>1)&1, j=(u-48)&1
//              k = kq*16 + j*8
//   u 60..63 : W_out: j=u-60; xc=t>>3, sl=t&7, k = sl*32 + j*8
constexpr int G_TOTAL = 64 * NT;  // 32768 uint4 = 512 KB

__device__ __forceinline__ float sigmoid_f(float x) {
  float e = __expf(fminf(-x, 80.f));
  return 1.f / (1.f + e);
}
__device__ __forceinline__ float tanh_f(float x) {
  float e = __expf(fminf(-2.f * x, 80.f));
  return (1.f - e) / (1.f + e);
}

__device__ __forceinline__ unsigned pk2(float a, float b) {
  h2_t v;
  v[0] = (_Float16)a;
  v[1] = (_Float16)b;
  return __builtin_bit_cast(unsigned, v);
}
__device__ __forceinline__ uint4 pk8(const float* s) {
  return make_uint4(pk2(s[0], s[1]), pk2(s[2], s[3]), pk2(s[4], s[5]),
                    pk2(s[6], s[7]));
}

// fp16-pair dot with fp32 accumulate (v_dot2_f32_f16)
__device__ __forceinline__ float dotp(unsigned w, unsigned h, float acc) {
  h2_t wv = __builtin_bit_cast(h2_t, w);
  h2_t hv = __builtin_bit_cast(h2_t, h);
#if __has_builtin(__builtin_amdgcn_fdot2)
  return __builtin_amdgcn_fdot2(wv, hv, acc, false);
#else
  acc = fmaf((float)wv[0], (float)hv[0], acc);
  return fmaf((float)wv[1], (float)hv[1], acc);
#endif
}
__device__ __forceinline__ float dotq(uint4 w, uint4 h, float acc) {
  acc = dotp(w.x, h.x, acc);
  acc = dotp(w.y, h.y, acc);
  acc = dotp(w.z, h.z, acc);
  acc = dotp(w.w, h.w, acc);
  return acc;
}

// DPP quad_perm: xor1 = 0xB1, xor2 = 0x4E (VALU-only lane exchange)
__device__ __forceinline__ float dpp_xor1(float x) {
  int v = __builtin_amdgcn_update_dpp(0, __builtin_bit_cast(int, x), 0xB1,
                                      0xF, 0xF, true);
  return __builtin_bit_cast(float, v);
}
__device__ __forceinline__ float dpp_xor2(float x) {
  int v = __builtin_amdgcn_update_dpp(0, __builtin_bit_cast(int, x), 0x4E,
                                      0xF, 0xF, true);
  return __builtin_bit_cast(float, v);
}
// full quad reduce: all 4 kq lanes end with the quad sum
#define QRED(v)       \
  v += dpp_xor1(v);   \
  v += dpp_xor2(v);

// Main-loop barrier: LDS-only drain, no vmcnt (out[] stores never read back)
__device__ __forceinline__ void bar_lds() {
  asm volatile("s_waitcnt lgkmcnt(0)\n\ts_barrier" ::: "memory");
}

// One-time fp32 -> fp16 pack + transpose into the register/LDS layouts.
__global__ void prep_kernel(const float* __restrict__ Wih,
                            const float* __restrict__ Whh,
                            const float* __restrict__ Wout,
                            uint4* __restrict__ G) {
  int id = blockIdx.x * 256 + threadIdx.x;
  if (id >= G_TOTAL) return;
  int t = id & (NT - 1), u = id >> 9;
  int cp = t >> 2, kq = t & 3, c0 = 2 * cp;
  if (u < 32) {  // W_hh r,z
    int g = u >> 4, col01 = (u >> 3) & 1, j = u & 7;
    G[id] = pk8(Whh + (size_t)(g * 256 + c0 + col01) * H_ + kq * 64 + j * 8);
  } else if (u < 48) {  // W_hh n (LDS stream)
    int v = u - 32, col01 = v >> 3, j = v & 7;
    G[id] = pk8(Whh + (size_t)(512 + c0 + col01) * H_ + kq * 64 + j * 8);
  } else if (u < 60) {  // W_ih
    int v = u - 48, g = v >> 2, col01 = (v >> 1) & 1, j = v & 1;
    G[id] = pk8(Wih + (size_t)(g * 256 + c0 + col01) * X_ + kq * 16 + j * 8);
  } else {  // W_out (unchanged from R13/R14)
    int j = u - 60, xc = t >> 3, sl = t & 7;
    G[id] = pk8(Wout + (size_t)xc * H_ + sl * 32 + j * 8);
  }
}

// ---- per-step building blocks (p/q compile-time 0/1 in the main loop) ----
// hid4: 4 kq-blocks x 36 words (32 data + 4 stagger) -> quad reads hit
// disjoint banks.  xt4: 4 blocks x 12 words.  pt2: 8 sl-blocks x 36 words.

#define GATES(p, i, hnA, hnB)                                                \
  float hnA, hnB;                                                            \
  {                                                                          \
    float arA = 0, arB = 0, azA = 0, azB = 0, anA = 0, anB = 0;              \
    float niA = 0, niB = 0;                                                  \
    const uint4* h4 = ((const uint4*)hid4[p]) + kq * 9;                      \
    _Pragma("unroll") for (int j = 0; j < 8; ++j) {                          \
      uint4 hj = h4[j];                                                      \
      uint4 wnA = wn_l[j * NT + t], wnB = wn_l[(8 + j) * NT + t];            \
      arA = dotq(whh_rz[j], hj, arA);                                        \
      arB = dotq(whh_rz[8 + j], hj, arB);                                    \
      azA = dotq(whh_rz[16 + j], hj, azA);                                   \
      azB = dotq(whh_rz[24 + j], hj, azB);                                   \
      anA = dotq(wnA, hj, anA);                                              \
      anB = dotq(wnB, hj, anB);                                              \
    }                                                                        \
    const uint4* x4 = ((const uint4*)xt4[p]) + kq * 3;                       \
    uint4 xa = x4[0], xb = x4[1];                                            \
    arA = dotq(wih[0], xa, arA);                                             \
    arA = dotq(wih[1], xb, arA);                                             \
    arB = dotq(wih[2], xa, arB);                                             \
    arB = dotq(wih[3], xb, arB);                                             \
    azA = dotq(wih[4], xa, azA);                                             \
    azA = dotq(wih[5], xb, azA);                                             \
    azB = dotq(wih[6], xa, azB);                                             \
    azB = dotq(wih[7], xb, azB);                                             \
    niA = dotq(wih[8], xa, niA);                                             \
    niA = dotq(wih[9], xb, niA);                                             \
    niB = dotq(wih[10], xa, niB);                                            \
    niB = dotq(wih[11], xb, niB);                                            \
    QRED(arA) QRED(arB) QRED(azA) QRED(azB)                                  \
    QRED(anA) QRED(anB) QRED(niA) QRED(niB)                                  \
    float rA = sigmoid_f(arA + bsrA);                                        \
    float zA = sigmoid_f(azA + bszA);                                        \
    float nA = tanh_f(niA + binA + rA * (anA + bhnA));                       \
    hnA = fmaf(zA, hidA - nA, nA);                                           \
    float rB = sigmoid_f(arB + bsrB);                                        \
    float zB = sigmoid_f(azB + bszB);                                        \
    float nB = tanh_f(niB + binB + rB * (anB + bhnB));                       \
    hnB = fmaf(zB, hidB - nB, nB);                                           \
    if (kq == 0) {                                                           \
      ring[(i) & (RS - 1)][c0] = hnA;                                        \
      ring[(i) & (RS - 1)][c0 + 1] = hnB;                                    \
    }                                                                        \
  }

#define PROJ_FIN(q, i)                                                       \
  {                                                                          \
    fa += dpp_xor1(fa);                                                      \
    fa += dpp_xor2(fa);                                                      \
    fa += __shfl_xor(fa, 4);                                                 \
    float o = fa + bo;                                                       \
    if (sl == 0) out[ob + (size_t)(i)*X_ + xc] = o;                          \
    float oo = __shfl_xor(o, 8);                                             \
    if ((t & 15) == 0)                                                       \
      ((unsigned*)xt4[q])[(xc >> 4) * 12 + ((xc & 15) >> 1)] = pk2(o, oo);   \
  }

#define PROJ(p, q, i)                                                        \
  {                                                                          \
    float fa = 0;                                                            \
    const uint4* p4 = (const uint4*)&pt2[p][sl * 36];                        \
    _Pragma("unroll") for (int j = 0; j < 4; ++j) fa =                       \
        dotq(wout[j], p4[j], fa);                                            \
    PROJ_FIN(q, i)                                                           \
  }

// Main-loop step (i >= 2*skip, skip >= 1): pt2[p] made at step i-1; PROJ is
// independent of GATES(i) -> its dots issue first to fill load latency.
#define MSTEP(i, p, q)                                                       \
  {                                                                          \
    float fa = 0;                                                            \
    const uint4* p4 = (const uint4*)&pt2[p][sl * 36];                        \
    _Pragma("unroll") for (int j = 0; j < 4; ++j) fa =                       \
        dotq(wout[j], p4[j], fa);                                            \
    GATES(p, i, hnA, hnB)                                                    \
    PROJ_FIN(q, i)                                                           \
    if ((i) + 1 < T_) {                                                      \
      int ri = ((i) + 1 - 2 * skip) & (RS - 1);                              \
      float sgA = ring[ri][c0], sgB = ring[ri][c0 + 1];                      \
      float m0v = m0f[(i) + 1], m1v = m1f[(i) + 1];                          \
      float hidnA = fmaf(m0v, hnA, m1v * sgA);                               \
      float hidnB = fmaf(m0v, hnB, m1v * sgB);                               \
      hidA = hidnA;                                                          \
      hidB = hidnB;                                                          \
      if (kq == 0) {                                                         \
        ((unsigned*)hid4[q])[(cp >> 5) * 36 + (cp & 31)] =                   \
            pk2(hidnA, hidnB);                                               \
        pt2[q][(cp >> 4) * 36 + (cp & 15)] = pk2(hnA + sgA, hnB + sgB);      \
      }                                                                      \
    }                                                                        \
    bar_lds();                                                               \
  }

__global__ __attribute__((amdgpu_flat_work_group_size(NT, NT),
                          amdgpu_waves_per_eu(2, 2))) void decoder_kernel(
    const float* __restrict__ h_enc, const float* __restrict__ b_ih,
    const float* __restrict__ b_hh, const float* __restrict__ b_out,
    const int* __restrict__ mask0, const int* __restrict__ mask1,
    const int* __restrict__ skipp, const uint4* __restrict__ G,
    float* __restrict__ out) {
  __shared__ alignas(16) uint4 wn_l[16 * NT];      // 128 KB W_hh n [v][t]
  __shared__ float ring[RS][H_];                   // 16 KB h history (fp32)
  __shared__ alignas(16) unsigned hid4[2][144];    // h fp16, 4 blk x 36 w
  __shared__ alignas(16) unsigned pt2[2][8 * 36];  // h_prev+skip, 8 blk x 36
  __shared__ alignas(16) unsigned xt4[2][48];      // x fp16, 4 blk x 12 w
  __shared__ float m0f[T_], m1f[T_];               // 4 KB masks
  // total: 131072+16384+1152+2304+384+4096 = 155392 B (151.8 KB)

  const int t = threadIdx.x;
  const int b = blockIdx.x;
  const int cp = t >> 2, kq = t & 3;  // gate role: col-pair, K-quarter
  const int c0 = 2 * cp;
  const int xc = t >> 3, sl = t & 7;  // projection role (unchanged)
  const size_t ob = (size_t)b * T_ * X_;

  // ---- resident weight registers: 48 uint4 = 192 regs/thread ----
  uint4 whh_rz[32];  // r,z x 2 cols x 64 K
  uint4 wih[12];     // 3 gates x 2 cols x 16 K
  uint4 wout[4];     // 32 K-slice of own xc column
#pragma unroll
  for (int u = 0; u < 32; ++u) whh_rz[u] = G[u * NT + t];
#pragma unroll
  for (int u = 0; u < 12; ++u) wih[u] = G[(48 + u) * NT + t];
#pragma unroll
  for (int u = 0; u < 4; ++u) wout[u] = G[(60 + u) * NT + t];

  // ---- LDS: n-gate weights + masks ----
#pragma unroll
  for (int u = 0; u < 16; ++u) wn_l[u * NT + t] = G[(32 + u) * NT + t];
  m0f[t] = (float)mask0[t];
  m1f[t] = (float)mask1[t];

  const int skip = skipp[0];
  const int i0 = (skip == 0) ? T_ : ((2 * skip < T_) ? 2 * skip : T_);

  const float bsrA = b_ih[c0] + b_hh[c0];
  const float bsrB = b_ih[c0 + 1] + b_hh[c0 + 1];
  const float bszA = b_ih[H_ + c0] + b_hh[H_ + c0];
  const float bszB = b_ih[H_ + c0 + 1] + b_hh[H_ + c0 + 1];
  const float binA = b_ih[2 * H_ + c0];
  const float binB = b_ih[2 * H_ + c0 + 1];
  const float bhnA = b_hh[2 * H_ + c0];
  const float bhnB = b_hh[2 * H_ + c0 + 1];
  const float bo = b_out[xc];

  float hpA = h_enc[(size_t)b * H_ + c0];
  float hpB = h_enc[(size_t)b * H_ + c0 + 1];
  const float m00 = (float)mask0[0];
  float hidA = m00 * hpA, hidB = m00 * hpB;  // hidden(0); skip_g(0) == 0
  float hpsA = hpA, hpsB = hpB;              // h_prev(0) = h_enc
  if (kq == 0) {
    ring[RS - 1][c0] = hpA;  // unused slot; harmless
    ring[RS - 1][c0 + 1] = hpB;
    ((unsigned*)hid4[0])[(cp >> 5) * 36 + (cp & 31)] = pk2(hidA, hidB);
  }
  if (t < 48) ((unsigned*)xt4[0])[t] = 0u;  // GO token
  __syncthreads();

  // ---- prologue: generic 2-barrier steps for i < 2*skip ----
  for (int i = 0; i < i0; ++i) {
    const int p = i & 1, q = p ^ 1;
    GATES(p, i, hnA, hnB)
    {
      int ppos = (i < skip) ? 2 * i + 1 : i - skip;
      bool pz = ppos < skip;
      int pi = ppos - skip;
      if (pi < 0) pi = 0;
      float spA, spB;
      if (pz) {
        spA = 0.f;
        spB = 0.f;
      } else if (pi == i) {
        spA = hnA;
        spB = hnB;
      } else {
        spA = ring[pi & (RS - 1)][c0];
        spB = ring[pi & (RS - 1)][c0 + 1];
      }
      if (kq == 0)
        pt2[p][(cp >> 4) * 36 + (cp & 15)] = pk2(hpsA + spA, hpsB + spB);
    }
    if (i + 1 < T_) {
      int i1 = i + 1;
      int pg = (i1 < skip) ? 2 * i1 : i1 - skip;
      bool gz = pg < skip;
      int gi = pg - skip;
      if (gi < 0) gi = 0;
      if (gi >= i1) gz = true;  // unwritten slot == reference zero init
      float sgA, sgB;
      if (gz) {
        sgA = 0.f;
        sgB = 0.f;
      } else if (gi == i) {
        sgA = hnA;
        sgB = hnB;
      } else {
        sgA = ring[gi & (RS - 1)][c0];
        sgB = ring[gi & (RS - 1)][c0 + 1];
      }
      float hidnA = m0f[i1] * hnA + m1f[i1] * sgA;
      float hidnB = m0f[i1] * hnB + m1f[i1] * sgB;
      hidA = hidnA;
      hidB = hidnB;
      if (kq == 0)
        ((unsigned*)hid4[q])[(cp >> 5) * 36 + (cp & 31)] = pk2(hidnA, hidnB);
      if (skip > 0 && i1 >= 2 * skip) {  // handoff into fused main loop
        int ri = (i1 - 2 * skip) & (RS - 1);
        float sgpA = ring[ri][c0], sgpB = ring[ri][c0 + 1];
        if (kq == 0)
          pt2[q][(cp >> 4) * 36 + (cp & 15)] = pk2(hnA + sgpA, hnB + sgpB);
      }
    }
    hpsA = hnA;
    hpsB = hnB;
    __syncthreads();
    PROJ(p, q, i)
    __syncthreads();
  }

  // ---- main loop: one lgkm-only barrier per step; i0 even -> parity static
#pragma unroll 1
  for (int i = i0; i < T_; i += 2) {
    MSTEP(i, 0, 1)
    MSTEP(i + 1, 1, 0)
  }
}

extern "C" void kernel_launch(void* const* d_in, const int* in_sizes, int n_in,
                              void* d_out, int out_size, void* d_ws,
                              size_t ws_size, hipStream_t stream) {
  (void)in_sizes; (void)n_in; (void)out_size; (void)ws_size;
  // d_in[0] = input [B,T,X] — unused by the reference computation.
  const float* h_enc = (const float*)d_in[1];
  const float* W_ih = (const float*)d_in[2];
  const float* W_hh = (const float*)d_in[3];
  const float* b_ih = (const float*)d_in[4];
  const float* b_hh = (const float*)d_in[5];
  const float* W_out = (const float*)d_in[6];
  const float* b_out = (const float*)d_in[7];
  const int* mask0 = (const int*)d_in[8];
  const int* mask1 = (const int*)d_in[9];
  const int* skipp = (const int*)d_in[10];
  float* out = (float*)d_out;
  uint4* G = (uint4*)d_ws;  // 512 KB fp16 weight image

  prep_kernel<<<dim3(G_TOTAL / 256), dim3(256), 0, stream>>>(W_ih, W_hh,
                                                             W_out, G);
  decoder_kernel<<<dim3(NWG), dim3(NT), 0, stream>>>(
      h_enc, b_ih, b_hh, b_out, mask0, mask1, skipp, G, out);
}